// Round 7
// baseline (156.311 us; speedup 1.0000x reference)
//
#include <hip/hip_runtime.h>
#include <hip/hip_bf16.h>

// 2-bit quantized embedding gather — persistent, barrier-free, 3-stage
// register software pipeline.
// VOCAB=400000, DIM=128, NBITS=2 -> token t owns 8 aligned int32 words
// bit_arr[8t..8t+7]; dim d -> word 8t + d/16, 2-bit code, out=codebook[code].
//
// History: R1 fused 166.7us -> R3 batched 163.8 -> R4 split-via-ws 152.5
// -> R5 (+nt) 155.3 -> R6 LDS-staged 149.5.
// R7: disambiguation — if R6's kernel had latency slack, this removes it:
// grid-stride persistent threads (32 items each), no barriers, pipeline
//   stage 0 (iter n): issue ids loads for iter n+2
//   stage 1 (iter n): issue bits loads for iter n+1 (ids arrived 1 iter ago)
//   stage 2 (iter n): decode + store iter n (words arrived 1 iter ago)
// Every load this iteration is independent of this iteration's decode, so
// the compiler's waitcnt on wC leaves the prefetches in flight.

#define EMB_DIM 128
#define BLOCK 256
#define GRID  1024     // 262,144 threads; 4 blocks/CU, 16 waves/CU
#define BATCH 4        // items per pipeline slot

typedef float vfloat4 __attribute__((ext_vector_type(4)));

__global__ __launch_bounds__(BLOCK) void embed2bit_pipe_kernel(
    const int* __restrict__ ids,      // [n_tokens] int32
    const int* __restrict__ bits,     // [3,200,000] packed int32
    const float* __restrict__ cb,     // [4] codebook
    float* __restrict__ out,          // [n_tokens*128] fp32
    int n_items)                      // n_tokens*32 (one float4 per item)
{
    const long long stride = (long long)gridDim.x * blockDim.x;   // 262,144
    const long long tid0   = (long long)blockIdx.x * blockDim.x + threadIdx.x;
    const long long step   = (long long)BATCH * stride;

    if (tid0 >= n_items) return;

    const float c0 = cb[0], c1 = cb[1], c2 = cb[2], c3 = cb[3];
    const long long last = n_items - 1;

    int tokC[BATCH], tokN[BATCH], wC[BATCH];

    // --- prologue: ids(iter0), ids(iter1), words(iter0) -------------------
#pragma unroll
    for (int j = 0; j < BATCH; ++j) {
        long long i = tid0 + (long long)j * stride; if (i > last) i = last;
        tokC[j] = ids[i >> 5];
    }
#pragma unroll
    for (int j = 0; j < BATCH; ++j) {
        long long i = tid0 + step + (long long)j * stride; if (i > last) i = last;
        tokN[j] = ids[i >> 5];
    }
#pragma unroll
    for (int j = 0; j < BATCH; ++j) {
        long long i = tid0 + (long long)j * stride; if (i > last) i = last;
        wC[j] = bits[(long long)tokC[j] * 8 + ((i & 31) >> 2)];
    }

    // --- steady state ------------------------------------------------------
    for (long long base = tid0; base < n_items; base += step) {
        int tokF[BATCH], wN[BATCH];
        // stage 0: ids for iter n+2 (independent)
#pragma unroll
        for (int j = 0; j < BATCH; ++j) {
            long long i = base + 2 * step + (long long)j * stride;
            if (i > last) i = last;
            tokF[j] = ids[i >> 5];
        }
        // stage 1: words for iter n+1 (tokN arrived one iteration ago)
#pragma unroll
        for (int j = 0; j < BATCH; ++j) {
            long long i = base + step + (long long)j * stride;
            if (i > last) i = last;
            wN[j] = bits[(long long)tokN[j] * 8 + ((i & 31) >> 2)];
        }
        // stage 2: decode + store iter n (wC arrived one iteration ago)
#pragma unroll
        for (int j = 0; j < BATCH; ++j) {
            long long i = base + (long long)j * stride;
            if (i >= n_items) break;
            int byte = (wC[j] >> (((int)i & 3) * 8)) & 0xff;
            vfloat4 r;
#pragma unroll
            for (int q = 0; q < 4; ++q) {
                int c    = (byte >> (2 * q)) & 3;
                float lo = (c & 1) ? c1 : c0;
                float hi = (c & 1) ? c3 : c2;
                r[q]     = (c & 2) ? hi : lo;   // 2x v_cndmask per element
            }
            // consecutive lanes -> contiguous 1KiB per wave-store
            *reinterpret_cast<vfloat4*>(out + i * 4) = r;
        }
        // rotate pipeline registers
#pragma unroll
        for (int j = 0; j < BATCH; ++j) { wC[j] = wN[j]; tokN[j] = tokF[j]; }
    }
}

extern "C" void kernel_launch(void* const* d_in, const int* in_sizes, int n_in,
                              void* d_out, int out_size, void* d_ws, size_t ws_size,
                              hipStream_t stream) {
    const int*   ids  = (const int*)d_in[0];
    const int*   bits = (const int*)d_in[1];
    const float* cb   = (const float*)d_in[2];
    float*       out  = (float*)d_out;

    int n_tokens = in_sizes[0];               // 262,144
    int n_items  = n_tokens * 32;             // 8,388,608 = 262,144 thr x 32

    long long want = ((long long)n_items + BLOCK - 1) / BLOCK;
    int grid = (int)(want < GRID ? want : GRID);

    embed2bit_pipe_kernel<<<grid, BLOCK, 0, stream>>>(ids, bits, cb, out, n_items);
}

// Round 8
// 151.043 us; speedup vs baseline: 1.0349x; 1.0349x over previous
//
#include <hip/hip_runtime.h>
#include <hip/hip_bf16.h>

// 2-bit quantized embedding gather, single kernel with per-block LDS staging.
// VOCAB=400000, DIM=128, NBITS=2 -> token t owns 8 aligned int32 words
// bit_arr[8t..8t+7] (32B row); dim d -> word 8t + d/16, 2-bit code,
// out = codebook[code].
//
// History: R1 fused 166.7us -> R3 batched 163.8 (neutral) -> R4 split-via-ws
// 152.5 -> R5 +nt/int4 155.3 (nt hurt) -> R6 LDS-staged 149.5 (best)
// -> R7 persistent 3-stage pipeline 156.3 (latency removal HURT).
// R8: revert to R6 verbatim. Evidence says R6 is at the traffic floor:
// only traffic-reduction changes ever helped, each by bytes/fill-rate;
// both latency-oriented designs (R3, R7) were neutral-or-worse.
//
// Block = 256 thr handles 64 tokens: phase 1 gathers 64 rows (2KB) into LDS
// via 128 int4 loads; phase 2 decodes 8 float4 items/thread and writes one
// contiguous 32KB chunk. 2KB LDS + low VGPR -> many blocks/CU resident, so
// the per-block gather/barrier latency is cross-block hidden (m114).

#define EMB_DIM 128
#define TOK_PER_BLOCK 64
#define BLOCK 256

typedef float vfloat4 __attribute__((ext_vector_type(4)));
typedef int   vint4   __attribute__((ext_vector_type(4)));

__global__ __launch_bounds__(BLOCK) void embed2bit_lds_kernel(
    const int* __restrict__ ids,      // [n_tokens] int32
    const int* __restrict__ bits,     // [3,200,000] packed int32
    const float* __restrict__ cb,     // [4] codebook
    float* __restrict__ out,          // [n_tokens, 128] fp32
    int n_tokens)
{
    __shared__ int lds_words[TOK_PER_BLOCK * 8];   // 2 KB: rows in token order

    const int t0  = blockIdx.x * TOK_PER_BLOCK;
    const int tid = threadIdx.x;

    // --- Phase 1: gather 64 token rows into LDS (128 threads x int4) -----
    if (tid < TOK_PER_BLOCK * 2) {
        int t = t0 + (tid >> 1);                  // 2 threads per token
        if (t < n_tokens) {
            int tok = ids[t];
            vint4 w = *reinterpret_cast<const vint4*>(
                bits + (long long)tok * 8 + (tid & 1) * 4);
            *reinterpret_cast<vint4*>(&lds_words[tid * 4]) = w;
        }
    }
    __syncthreads();

    // --- Phase 2: decode + contiguous stores (8 float4 items / thread) ---
    const float c0 = cb[0], c1 = cb[1], c2 = cb[2], c3 = cb[3];
    const long long out_base = (long long)t0 * EMB_DIM;
    const int n_items = (n_tokens - t0 >= TOK_PER_BLOCK
                             ? TOK_PER_BLOCK : n_tokens - t0) * 32;

#pragma unroll
    for (int q = 0; q < 8; ++q) {
        int item = q * BLOCK + tid;               // [0, 2048)
        if (item >= n_items) break;
        int word = lds_words[item >> 2];          // 4 lanes broadcast a word
        int byte = (word >> ((item & 3) * 8)) & 0xff;

        vfloat4 r;
#pragma unroll
        for (int j = 0; j < 4; ++j) {
            int c    = (byte >> (2 * j)) & 3;
            float lo = (c & 1) ? c1 : c0;
            float hi = (c & 1) ? c3 : c2;
            r[j]     = (c & 2) ? hi : lo;         // 2x v_cndmask per element
        }
        // item*16B: consecutive lanes -> contiguous 4KB per wave-store.
        *reinterpret_cast<vfloat4*>(out + out_base + (long long)item * 4) = r;
    }
}

extern "C" void kernel_launch(void* const* d_in, const int* in_sizes, int n_in,
                              void* d_out, int out_size, void* d_ws, size_t ws_size,
                              hipStream_t stream) {
    const int*   ids  = (const int*)d_in[0];
    const int*   bits = (const int*)d_in[1];
    const float* cb   = (const float*)d_in[2];
    float*       out  = (float*)d_out;

    int n_tokens = in_sizes[0];                   // 262,144
    int grid = (n_tokens + TOK_PER_BLOCK - 1) / TOK_PER_BLOCK;   // 4096

    embed2bit_lds_kernel<<<grid, BLOCK, 0, stream>>>(ids, bits, cb, out, n_tokens);
}